// Round 1
// baseline (4986.784 us; speedup 1.0000x reference)
//
#include <hip/hip_runtime.h>

#define DIM 128
#define N_GRAPHS 64
#define MM_ROWS 64

// ---------------- degree / norm precompute ----------------

__global__ void k_deg_init(float* __restrict__ deg, int n) {
    int i = blockIdx.x * blockDim.x + threadIdx.x;
    if (i < n) deg[i] = 1.0f;  // self loop
}

__global__ void k_deg_count(const int* __restrict__ col, float* __restrict__ deg, int e) {
    int i = blockIdx.x * blockDim.x + threadIdx.x;
    if (i < e) unsafeAtomicAdd(&deg[col[i]], 1.0f);
}

__global__ void k_make_dis(float* __restrict__ deg, int n) {
    int i = blockIdx.x * blockDim.x + threadIdx.x;
    if (i < n) deg[i] = rsqrtf(deg[i]);
}

__global__ void k_make_norm(const int* __restrict__ row, const int* __restrict__ col,
                            const float* __restrict__ dis, float* __restrict__ norm, int e) {
    int i = blockIdx.x * blockDim.x + threadIdx.x;
    if (i < e) norm[i] = dis[row[i]] * dis[col[i]];
}

// ---------------- aggregation (A+I with sym norm) ----------------

// self-loop term, fully initializes agg (no zeroing required)
__global__ void k_agg_self(const float* __restrict__ in, const float* __restrict__ dis,
                           float* __restrict__ agg, int n) {
    int idx = blockIdx.x * blockDim.x + threadIdx.x;
    int i = idx >> 5;
    if (i >= n) return;
    int c = (idx & 31) * 4;
    float s = dis[i];
    s = s * s;
    float4 v = *(const float4*)&in[(size_t)i * DIM + c];
    v.x *= s; v.y *= s; v.z *= s; v.w *= s;
    *(float4*)&agg[(size_t)i * DIM + c] = v;
}

// edge scatter: 32 lanes per edge, float4 gather + 4 f32 atomics
__global__ void k_agg_edges(const float* __restrict__ in, const int* __restrict__ row,
                            const int* __restrict__ col, const float* __restrict__ norm,
                            float* __restrict__ agg, int e) {
    int idx = blockIdx.x * blockDim.x + threadIdx.x;
    int ei = idx >> 5;
    if (ei >= e) return;
    int c = (idx & 31) * 4;
    int r = row[ei];
    int t = col[ei];
    float s = norm[ei];
    float4 v = *(const float4*)&in[(size_t)r * DIM + c];
    float* dst = &agg[(size_t)t * DIM + c];
    unsafeAtomicAdd(dst + 0, v.x * s);
    unsafeAtomicAdd(dst + 1, v.y * s);
    unsafeAtomicAdd(dst + 2, v.z * s);
    unsafeAtomicAdd(dst + 3, v.w * s);
}

// ---------------- matmul + bias + relu ----------------
// out[r][:] = relu(A[r][:] @ W + b), W staged in LDS (64 KB), wave-per-row

__global__ __launch_bounds__(256) void k_mm_bias_relu(
        const float* __restrict__ A, const float* __restrict__ W,
        const float* __restrict__ bias, float* __restrict__ out, int n) {
    __shared__ float sW[DIM * DIM];  // 64 KB
    int tid = threadIdx.x;
    for (int i = tid * 4; i < DIM * DIM; i += 256 * 4) {
        *(float4*)&sW[i] = *(const float4*)&W[i];
    }
    __syncthreads();

    int wave = tid >> 6, lane = tid & 63;
    int base = blockIdx.x * MM_ROWS;
    for (int rr = wave; rr < MM_ROWS; rr += 4) {
        int r = base + rr;
        if (r >= n) break;
        const float* xr = &A[(size_t)r * DIM];
        float x0 = xr[lane];
        float x1 = xr[lane + 64];
        float acc0 = 0.f, acc1 = 0.f;
#pragma unroll 8
        for (int k = 0; k < 64; k++) {
            float xk = __shfl(x0, k);
            acc0 += xk * sW[k * DIM + lane];
            acc1 += xk * sW[k * DIM + lane + 64];
        }
#pragma unroll 8
        for (int k = 0; k < 64; k++) {
            float xk = __shfl(x1, k);
            acc0 += xk * sW[(k + 64) * DIM + lane];
            acc1 += xk * sW[(k + 64) * DIM + lane + 64];
        }
        float o0 = acc0 + bias[lane];
        float o1 = acc1 + bias[lane + 64];
        out[(size_t)r * DIM + lane] = o0 > 0.f ? o0 : 0.f;
        out[(size_t)r * DIM + lane + 64] = o1 > 0.f ? o1 : 0.f;
    }
}

// ---------------- global mean pool ----------------

__global__ void k_pool_zero(float* __restrict__ pool, float* __restrict__ cnt) {
    int i = blockIdx.x * blockDim.x + threadIdx.x;
    if (i < N_GRAPHS * DIM) pool[i] = 0.f;
    if (i < N_GRAPHS) cnt[i] = 0.f;
}

__global__ void k_pool_sum(const float* __restrict__ h, const int* __restrict__ batch,
                           float* __restrict__ pool, float* __restrict__ cnt, int n) {
    int idx = blockIdx.x * blockDim.x + threadIdx.x;
    int i = idx >> 5;
    if (i >= n) return;
    int c = (idx & 31) * 4;
    int g = batch[i];
    float4 v = *(const float4*)&h[(size_t)i * DIM + c];
    float* dst = &pool[g * DIM + c];
    unsafeAtomicAdd(dst + 0, v.x);
    unsafeAtomicAdd(dst + 1, v.y);
    unsafeAtomicAdd(dst + 2, v.z);
    unsafeAtomicAdd(dst + 3, v.w);
    if ((idx & 31) == 0) unsafeAtomicAdd(&cnt[g], 1.0f);
}

__global__ void k_pool_div(const float* __restrict__ pool, const float* __restrict__ cnt,
                           float* __restrict__ out) {
    int i = blockIdx.x * blockDim.x + threadIdx.x;
    if (i < N_GRAPHS * DIM) {
        float c = cnt[i >> 7];
        c = c > 1.f ? c : 1.f;
        out[i] = pool[i] / c;
    }
}

// ---------------- launch ----------------

extern "C" void kernel_launch(void* const* d_in, const int* in_sizes, int n_in,
                              void* d_out, int out_size, void* d_ws, size_t ws_size,
                              hipStream_t stream) {
    const float* x  = (const float*)d_in[0];
    const int*   ei = (const int*)d_in[1];
    const int*   batch = (const int*)d_in[2];
    const float* W1 = (const float*)d_in[3];
    const float* b1 = (const float*)d_in[4];
    const float* W2 = (const float*)d_in[5];
    const float* b2 = (const float*)d_in[6];
    const float* W3 = (const float*)d_in[7];
    const float* b3 = (const float*)d_in[8];

    int n = in_sizes[0] / DIM;  // 50000
    int e = in_sizes[1] / 2;    // 800000
    const int* erow = ei;       // edge_index[0] = sources
    const int* ecol = ei + e;   // edge_index[1] = targets

    char* ws = (char*)d_ws;
    size_t off = 0;
    auto alloc = [&](size_t bytes) -> float* {
        float* p = (float*)(ws + off);
        off += (bytes + 255) & ~(size_t)255;
        return p;
    };
    float* dis  = alloc((size_t)n * 4);
    float* norm = alloc((size_t)e * 4);
    float* agg  = alloc((size_t)n * DIM * 4);
    float* bufA = alloc((size_t)n * DIM * 4);
    float* bufB = alloc((size_t)n * DIM * 4);
    float* pool = alloc((size_t)N_GRAPHS * DIM * 4);
    float* cnt  = alloc((size_t)N_GRAPHS * 4);

    // degree / norm precompute (edge_index is layer-invariant)
    k_deg_init<<<(n + 255) / 256, 256, 0, stream>>>(dis, n);
    k_deg_count<<<(e + 255) / 256, 256, 0, stream>>>(ecol, dis, e);
    k_make_dis<<<(n + 255) / 256, 256, 0, stream>>>(dis, n);
    k_make_norm<<<(e + 255) / 256, 256, 0, stream>>>(erow, ecol, dis, norm, e);

    dim3 nodeGrid(((size_t)n * 32 + 255) / 256);
    dim3 edgeGrid(((size_t)e * 32 + 255) / 256);
    dim3 mmGrid((n + MM_ROWS - 1) / MM_ROWS);

    // layer 1: agg(x) -> @W1 + b1, relu
    k_agg_self<<<nodeGrid, 256, 0, stream>>>(x, dis, agg, n);
    k_agg_edges<<<edgeGrid, 256, 0, stream>>>(x, erow, ecol, norm, agg, e);
    k_mm_bias_relu<<<mmGrid, 256, 0, stream>>>(agg, W1, b1, bufA, n);
    // layer 2
    k_agg_self<<<nodeGrid, 256, 0, stream>>>(bufA, dis, agg, n);
    k_agg_edges<<<edgeGrid, 256, 0, stream>>>(bufA, erow, ecol, norm, agg, e);
    k_mm_bias_relu<<<mmGrid, 256, 0, stream>>>(agg, W2, b2, bufB, n);
    // layer 3
    k_agg_self<<<nodeGrid, 256, 0, stream>>>(bufB, dis, agg, n);
    k_agg_edges<<<edgeGrid, 256, 0, stream>>>(bufB, erow, ecol, norm, agg, e);
    k_mm_bias_relu<<<mmGrid, 256, 0, stream>>>(agg, W3, b3, bufA, n);

    // global mean pool
    k_pool_zero<<<(N_GRAPHS * DIM + 255) / 256, 256, 0, stream>>>(pool, cnt);
    k_pool_sum<<<nodeGrid, 256, 0, stream>>>(bufA, batch, pool, cnt, n);
    k_pool_div<<<(N_GRAPHS * DIM + 255) / 256, 256, 0, stream>>>(pool, cnt, (float*)d_out);
}

// Round 2
// 1429.221 us; speedup vs baseline: 3.4892x; 3.4892x over previous
//
#include <hip/hip_runtime.h>

#define DIM 128
#define N_GRAPHS 64
#define MM_ROWS 64
#define SCAN_T 1024

// ---------------- degree / CSR precompute ----------------

__global__ void k_init(float* __restrict__ deg, int* __restrict__ cnt, int n) {
    int i = blockIdx.x * blockDim.x + threadIdx.x;
    if (i < n) { deg[i] = 1.0f; cnt[i] = 0; }  // self loop counts 1
}

__global__ void k_count(const int* __restrict__ col, float* __restrict__ deg,
                        int* __restrict__ cnt, int e) {
    int i = blockIdx.x * blockDim.x + threadIdx.x;
    if (i < e) {
        int t = col[i];
        unsafeAtomicAdd(&deg[t], 1.0f);
        atomicAdd(&cnt[t], 1);
    }
}

__global__ void k_make_dis(float* __restrict__ deg, int n) {
    int i = blockIdx.x * blockDim.x + threadIdx.x;
    if (i < n) deg[i] = rsqrtf(deg[i]);
}

// single-block exclusive scan: cnt[n] -> rowptr[n+1], cursor[n]
__global__ __launch_bounds__(SCAN_T) void k_scan(const int* __restrict__ cnt,
        int* __restrict__ rowptr, int* __restrict__ cursor, int n) {
    __shared__ int sums[SCAN_T];
    int t = threadIdx.x;
    int chunk = (n + SCAN_T - 1) / SCAN_T;
    int lo = t * chunk, hi = min(lo + chunk, n);
    int s = 0;
    for (int i = lo; i < hi; i++) s += cnt[i];
    sums[t] = s;
    __syncthreads();
    for (int off = 1; off < SCAN_T; off <<= 1) {
        int v = (t >= off) ? sums[t - off] : 0;
        __syncthreads();
        sums[t] += v;
        __syncthreads();
    }
    int base = (t == 0) ? 0 : sums[t - 1];
    for (int i = lo; i < hi; i++) {
        rowptr[i] = base;
        cursor[i] = base;
        base += cnt[i];
    }
    if (t == SCAN_T - 1) rowptr[n] = base;
}

__global__ void k_fill(const int* __restrict__ row, const int* __restrict__ col,
                       int* __restrict__ cursor, int* __restrict__ csr_src, int e) {
    int i = blockIdx.x * blockDim.x + threadIdx.x;
    if (i >= e) return;
    int pos = atomicAdd(&cursor[col[i]], 1);
    csr_src[pos] = row[i];
}

// ---------------- aggregation: gather form, no atomics ----------------
// one wave per target node; lane l owns columns [2l, 2l+1]

__global__ __launch_bounds__(256) void k_gcn_agg(const float* __restrict__ in,
        const int* __restrict__ csr_src, const int* __restrict__ rowptr,
        const float* __restrict__ dis, float* __restrict__ agg, int n) {
    int wid = (blockIdx.x * blockDim.x + threadIdx.x) >> 6;
    if (wid >= n) return;
    int lane = threadIdx.x & 63;
    float d = dis[wid];
    float2 acc = *(const float2*)&in[(size_t)wid * DIM + lane * 2];
    float dd = d * d;  // self-loop weight
    acc.x *= dd; acc.y *= dd;
    int p0 = rowptr[wid], p1 = rowptr[wid + 1];
    for (int p = p0; p < p1; p++) {
        int src = csr_src[p];                 // wave-uniform
        float w = d * dis[src];               // wave-uniform, L1/L2-hit
        float2 v = *(const float2*)&in[(size_t)src * DIM + lane * 2];  // 512B coalesced
        acc.x += v.x * w;
        acc.y += v.y * w;
    }
    *(float2*)&agg[(size_t)wid * DIM + lane * 2] = acc;
}

// ---------------- matmul + bias + relu ----------------

__global__ __launch_bounds__(256) void k_mm_bias_relu(
        const float* __restrict__ A, const float* __restrict__ W,
        const float* __restrict__ bias, float* __restrict__ out, int n) {
    __shared__ float sW[DIM * DIM];  // 64 KB
    int tid = threadIdx.x;
    for (int i = tid * 4; i < DIM * DIM; i += 256 * 4) {
        *(float4*)&sW[i] = *(const float4*)&W[i];
    }
    __syncthreads();

    int wave = tid >> 6, lane = tid & 63;
    int base = blockIdx.x * MM_ROWS;
    for (int rr = wave; rr < MM_ROWS; rr += 4) {
        int r = base + rr;
        if (r >= n) break;
        const float* xr = &A[(size_t)r * DIM];
        float x0 = xr[lane];
        float x1 = xr[lane + 64];
        float acc0 = 0.f, acc1 = 0.f;
#pragma unroll 8
        for (int k = 0; k < 64; k++) {
            float xk = __shfl(x0, k);
            acc0 += xk * sW[k * DIM + lane];
            acc1 += xk * sW[k * DIM + lane + 64];
        }
#pragma unroll 8
        for (int k = 0; k < 64; k++) {
            float xk = __shfl(x1, k);
            acc0 += xk * sW[(k + 64) * DIM + lane];
            acc1 += xk * sW[(k + 64) * DIM + lane + 64];
        }
        float o0 = acc0 + bias[lane];
        float o1 = acc1 + bias[lane + 64];
        out[(size_t)r * DIM + lane] = o0 > 0.f ? o0 : 0.f;
        out[(size_t)r * DIM + lane + 64] = o1 > 0.f ? o1 : 0.f;
    }
}

// ---------------- global mean pool ----------------

__global__ void k_pool_zero(float* __restrict__ pool, float* __restrict__ cnt) {
    int i = blockIdx.x * blockDim.x + threadIdx.x;
    if (i < N_GRAPHS * DIM) pool[i] = 0.f;
    if (i < N_GRAPHS) cnt[i] = 0.f;
}

__global__ void k_pool_sum(const float* __restrict__ h, const int* __restrict__ batch,
                           float* __restrict__ pool, float* __restrict__ cnt, int n) {
    int idx = blockIdx.x * blockDim.x + threadIdx.x;
    int i = idx >> 5;
    if (i >= n) return;
    int c = (idx & 31) * 4;
    int g = batch[i];
    float4 v = *(const float4*)&h[(size_t)i * DIM + c];
    float* dst = &pool[g * DIM + c];
    unsafeAtomicAdd(dst + 0, v.x);
    unsafeAtomicAdd(dst + 1, v.y);
    unsafeAtomicAdd(dst + 2, v.z);
    unsafeAtomicAdd(dst + 3, v.w);
    if ((idx & 31) == 0) unsafeAtomicAdd(&cnt[g], 1.0f);
}

__global__ void k_pool_div(const float* __restrict__ pool, const float* __restrict__ cnt,
                           float* __restrict__ out) {
    int i = blockIdx.x * blockDim.x + threadIdx.x;
    if (i < N_GRAPHS * DIM) {
        float c = cnt[i >> 7];
        c = c > 1.f ? c : 1.f;
        out[i] = pool[i] / c;
    }
}

// ---------------- launch ----------------

extern "C" void kernel_launch(void* const* d_in, const int* in_sizes, int n_in,
                              void* d_out, int out_size, void* d_ws, size_t ws_size,
                              hipStream_t stream) {
    const float* x  = (const float*)d_in[0];
    const int*   ei = (const int*)d_in[1];
    const int*   batch = (const int*)d_in[2];
    const float* W1 = (const float*)d_in[3];
    const float* b1 = (const float*)d_in[4];
    const float* W2 = (const float*)d_in[5];
    const float* b2 = (const float*)d_in[6];
    const float* W3 = (const float*)d_in[7];
    const float* b3 = (const float*)d_in[8];

    int n = in_sizes[0] / DIM;  // 50000
    int e = in_sizes[1] / 2;    // 800000
    const int* erow = ei;       // sources
    const int* ecol = ei + e;   // targets

    char* ws = (char*)d_ws;
    size_t off = 0;
    auto alloc = [&](size_t bytes) -> void* {
        void* p = (void*)(ws + off);
        off += (bytes + 255) & ~(size_t)255;
        return p;
    };
    float* dis     = (float*)alloc((size_t)n * 4);
    int*   rowptr  = (int*)alloc((size_t)(n + 1) * 4);
    int*   csr_src = (int*)alloc((size_t)e * 4);
    float* agg     = (float*)alloc((size_t)n * DIM * 4);
    float* bufA    = (float*)alloc((size_t)n * DIM * 4);
    float* bufB    = (float*)alloc((size_t)n * DIM * 4);
    float* pool    = (float*)alloc((size_t)N_GRAPHS * DIM * 4);
    float* cntf    = (float*)alloc((size_t)N_GRAPHS * 4);
    // transient CSR-build arrays overlap bufA (written only later, in layer-1 mm)
    int* cnt    = (int*)bufA;
    int* cursor = (int*)(bufA + n);

    // ---- CSR build (once; edge_index is layer-invariant) ----
    k_init<<<(n + 255) / 256, 256, 0, stream>>>(dis, cnt, n);
    k_count<<<(e + 255) / 256, 256, 0, stream>>>(ecol, dis, cnt, e);
    k_make_dis<<<(n + 255) / 256, 256, 0, stream>>>(dis, n);
    k_scan<<<1, SCAN_T, 0, stream>>>(cnt, rowptr, cursor, n);
    k_fill<<<(e + 255) / 256, 256, 0, stream>>>(erow, ecol, cursor, csr_src, e);

    dim3 aggGrid(((size_t)n * 64 + 255) / 256);
    dim3 mmGrid((n + MM_ROWS - 1) / MM_ROWS);
    dim3 poolGrid(((size_t)n * 32 + 255) / 256);

    // layer 1
    k_gcn_agg<<<aggGrid, 256, 0, stream>>>(x, csr_src, rowptr, dis, agg, n);
    k_mm_bias_relu<<<mmGrid, 256, 0, stream>>>(agg, W1, b1, bufA, n);
    // layer 2
    k_gcn_agg<<<aggGrid, 256, 0, stream>>>(bufA, csr_src, rowptr, dis, agg, n);
    k_mm_bias_relu<<<mmGrid, 256, 0, stream>>>(agg, W2, b2, bufB, n);
    // layer 3
    k_gcn_agg<<<aggGrid, 256, 0, stream>>>(bufB, csr_src, rowptr, dis, agg, n);
    k_mm_bias_relu<<<mmGrid, 256, 0, stream>>>(agg, W3, b3, bufA, n);

    // global mean pool
    k_pool_zero<<<(N_GRAPHS * DIM + 255) / 256, 256, 0, stream>>>(pool, cntf);
    k_pool_sum<<<poolGrid, 256, 0, stream>>>(bufA, batch, pool, cntf, n);
    k_pool_div<<<(N_GRAPHS * DIM + 255) / 256, 256, 0, stream>>>(pool, cntf, (float*)d_out);
}

// Round 3
// 808.033 us; speedup vs baseline: 6.1715x; 1.7688x over previous
//
#include <hip/hip_runtime.h>

#define DIM 128
#define N_GRAPHS 64
#define MM_ROWS 64
#define SCAN_T 1024

// ---------------- degree / CSR precompute ----------------

__global__ void k_init(float* __restrict__ deg, int* __restrict__ cnt, int n) {
    int i = blockIdx.x * blockDim.x + threadIdx.x;
    if (i < n) { deg[i] = 1.0f; cnt[i] = 0; }  // self loop counts 1
}

__global__ void k_count(const int* __restrict__ col, float* __restrict__ deg,
                        int* __restrict__ cnt, int e) {
    int i = blockIdx.x * blockDim.x + threadIdx.x;
    if (i < e) {
        int t = col[i];
        unsafeAtomicAdd(&deg[t], 1.0f);
        atomicAdd(&cnt[t], 1);
    }
}

__global__ void k_make_dis(float* __restrict__ deg, int n) {
    int i = blockIdx.x * blockDim.x + threadIdx.x;
    if (i < n) deg[i] = rsqrtf(deg[i]);
}

// single-block exclusive scan: cnt[n] -> rowptr[n+1], cursor[n]
__global__ __launch_bounds__(SCAN_T) void k_scan(const int* __restrict__ cnt,
        int* __restrict__ rowptr, int* __restrict__ cursor, int n) {
    __shared__ int sums[SCAN_T];
    int t = threadIdx.x;
    int chunk = (n + SCAN_T - 1) / SCAN_T;
    int lo = t * chunk, hi = min(lo + chunk, n);
    int s = 0;
    for (int i = lo; i < hi; i++) s += cnt[i];
    sums[t] = s;
    __syncthreads();
    for (int off = 1; off < SCAN_T; off <<= 1) {
        int v = (t >= off) ? sums[t - off] : 0;
        __syncthreads();
        sums[t] += v;
        __syncthreads();
    }
    int base = (t == 0) ? 0 : sums[t - 1];
    for (int i = lo; i < hi; i++) {
        rowptr[i] = base;
        cursor[i] = base;
        base += cnt[i];
    }
    if (t == SCAN_T - 1) rowptr[n] = base;
}

__global__ void k_fill(const int* __restrict__ row, const int* __restrict__ col,
                       int* __restrict__ cursor, int* __restrict__ csr_src, int e) {
    int i = blockIdx.x * blockDim.x + threadIdx.x;
    if (i >= e) return;
    int pos = atomicAdd(&cursor[col[i]], 1);
    csr_src[pos] = row[i];
}

// ---------------- aggregation: gather form, no atomics ----------------
// one wave per target node; lane l owns columns [2l, 2l+1]

__global__ __launch_bounds__(256) void k_gcn_agg(const float* __restrict__ in,
        const int* __restrict__ csr_src, const int* __restrict__ rowptr,
        const float* __restrict__ dis, float* __restrict__ agg, int n) {
    int wid = (blockIdx.x * blockDim.x + threadIdx.x) >> 6;
    if (wid >= n) return;
    int lane = threadIdx.x & 63;
    float d = dis[wid];
    float2 acc = *(const float2*)&in[(size_t)wid * DIM + lane * 2];
    float dd = d * d;  // self-loop weight
    acc.x *= dd; acc.y *= dd;
    int p0 = rowptr[wid], p1 = rowptr[wid + 1];
    for (int p = p0; p < p1; p++) {
        int src = csr_src[p];                 // wave-uniform
        float w = d * dis[src];               // wave-uniform, L1/L2-hit
        float2 v = *(const float2*)&in[(size_t)src * DIM + lane * 2];  // 512B coalesced
        acc.x += v.x * w;
        acc.y += v.y * w;
    }
    *(float2*)&agg[(size_t)wid * DIM + lane * 2] = acc;
}

// ---------------- matmul + bias + relu ----------------
// 2 rows per wave (half-waves), lane owns 4 adjacent cols -> ds_read_b128 for W

__global__ __launch_bounds__(256) void k_mm_bias_relu(
        const float* __restrict__ A, const float* __restrict__ W,
        const float* __restrict__ bias, float* __restrict__ out, int n) {
    __shared__ float sW[DIM * DIM];  // 64 KB
    int tid = threadIdx.x;
    for (int i = tid * 4; i < DIM * DIM; i += 256 * 4) {
        *(float4*)&sW[i] = *(const float4*)&W[i];
    }
    __syncthreads();

    int wave = tid >> 6, lane = tid & 63;
    int half = lane >> 5;        // 0 or 1: which row of the pair
    int l32 = lane & 31;         // owns cols [4*l32, 4*l32+3]
    int hsel = lane & 32;        // shfl half-select
    float4 bv = *(const float4*)&bias[4 * l32];
    int base = blockIdx.x * MM_ROWS;

    for (int pr = wave; pr < MM_ROWS / 2; pr += 4) {
        int r = base + pr * 2 + half;
        bool valid = (r < n);
        const float* xr = &A[(size_t)(valid ? r : (n - 1)) * DIM];
        float x0 = xr[l32];
        float x1 = xr[l32 + 32];
        float x2 = xr[l32 + 64];
        float x3 = xr[l32 + 96];
        float4 acc = {0.f, 0.f, 0.f, 0.f};

#pragma unroll 8
        for (int k = 0; k < 32; k++) {
            float xk = __shfl(x0, k + hsel);
            float4 wv = *(const float4*)&sW[k * DIM + 4 * l32];
            acc.x += xk * wv.x; acc.y += xk * wv.y;
            acc.z += xk * wv.z; acc.w += xk * wv.w;
        }
#pragma unroll 8
        for (int k = 0; k < 32; k++) {
            float xk = __shfl(x1, k + hsel);
            float4 wv = *(const float4*)&sW[(k + 32) * DIM + 4 * l32];
            acc.x += xk * wv.x; acc.y += xk * wv.y;
            acc.z += xk * wv.z; acc.w += xk * wv.w;
        }
#pragma unroll 8
        for (int k = 0; k < 32; k++) {
            float xk = __shfl(x2, k + hsel);
            float4 wv = *(const float4*)&sW[(k + 64) * DIM + 4 * l32];
            acc.x += xk * wv.x; acc.y += xk * wv.y;
            acc.z += xk * wv.z; acc.w += xk * wv.w;
        }
#pragma unroll 8
        for (int k = 0; k < 32; k++) {
            float xk = __shfl(x3, k + hsel);
            float4 wv = *(const float4*)&sW[(k + 96) * DIM + 4 * l32];
            acc.x += xk * wv.x; acc.y += xk * wv.y;
            acc.z += xk * wv.z; acc.w += xk * wv.w;
        }

        if (valid) {
            float4 o;
            o.x = acc.x + bv.x; o.y = acc.y + bv.y;
            o.z = acc.z + bv.z; o.w = acc.w + bv.w;
            o.x = o.x > 0.f ? o.x : 0.f;
            o.y = o.y > 0.f ? o.y : 0.f;
            o.z = o.z > 0.f ? o.z : 0.f;
            o.w = o.w > 0.f ? o.w : 0.f;
            *(float4*)&out[(size_t)r * DIM + 4 * l32] = o;
        }
    }
}

// ---------------- global mean pool: one block per graph, no atomics ----------------

__global__ __launch_bounds__(256) void k_pool_graph(const float* __restrict__ h,
        const int* __restrict__ batch, float* __restrict__ out, int n) {
    int g = blockIdx.x;
    // lower_bound(batch, g)
    int lo = 0, hi = n;
    while (lo < hi) { int m = (lo + hi) >> 1; if (batch[m] < g) lo = m + 1; else hi = m; }
    int start = lo;
    // lower_bound(batch, g+1)
    int lo2 = start, hi2 = n;
    while (lo2 < hi2) { int m = (lo2 + hi2) >> 1; if (batch[m] < g + 1) lo2 = m + 1; else hi2 = m; }
    int end = lo2;

    int t = threadIdx.x;
    int wave = t >> 6, lane = t & 63;
    float2 acc = {0.f, 0.f};
    for (int r = start + wave; r < end; r += 4) {
        float2 v = *(const float2*)&h[(size_t)r * DIM + lane * 2];
        acc.x += v.x; acc.y += v.y;
    }
    __shared__ float2 part[4][64];
    part[wave][lane] = acc;
    __syncthreads();
    if (t < 64) {
        float2 s0 = part[0][t], s1 = part[1][t], s2 = part[2][t], s3 = part[3][t];
        float sx = s0.x + s1.x + s2.x + s3.x;
        float sy = s0.y + s1.y + s2.y + s3.y;
        float c = (float)(end - start);
        c = c > 1.f ? c : 1.f;
        out[g * DIM + t * 2] = sx / c;
        out[g * DIM + t * 2 + 1] = sy / c;
    }
}

// ---------------- launch ----------------

extern "C" void kernel_launch(void* const* d_in, const int* in_sizes, int n_in,
                              void* d_out, int out_size, void* d_ws, size_t ws_size,
                              hipStream_t stream) {
    const float* x  = (const float*)d_in[0];
    const int*   ei = (const int*)d_in[1];
    const int*   batch = (const int*)d_in[2];
    const float* W1 = (const float*)d_in[3];
    const float* b1 = (const float*)d_in[4];
    const float* W2 = (const float*)d_in[5];
    const float* b2 = (const float*)d_in[6];
    const float* W3 = (const float*)d_in[7];
    const float* b3 = (const float*)d_in[8];

    int n = in_sizes[0] / DIM;  // 50000
    int e = in_sizes[1] / 2;    // 800000
    const int* erow = ei;       // sources
    const int* ecol = ei + e;   // targets

    char* ws = (char*)d_ws;
    size_t off = 0;
    auto alloc = [&](size_t bytes) -> void* {
        void* p = (void*)(ws + off);
        off += (bytes + 255) & ~(size_t)255;
        return p;
    };
    float* dis     = (float*)alloc((size_t)n * 4);
    int*   rowptr  = (int*)alloc((size_t)(n + 1) * 4);
    int*   csr_src = (int*)alloc((size_t)e * 4);
    float* agg     = (float*)alloc((size_t)n * DIM * 4);
    float* bufA    = (float*)alloc((size_t)n * DIM * 4);
    float* bufB    = (float*)alloc((size_t)n * DIM * 4);
    // transient CSR-build arrays overlap bufA (written only later, in layer-1 mm)
    int* cnt    = (int*)bufA;
    int* cursor = (int*)(bufA + n);

    // ---- CSR build (once; edge_index is layer-invariant) ----
    k_init<<<(n + 255) / 256, 256, 0, stream>>>(dis, cnt, n);
    k_count<<<(e + 255) / 256, 256, 0, stream>>>(ecol, dis, cnt, e);
    k_make_dis<<<(n + 255) / 256, 256, 0, stream>>>(dis, n);
    k_scan<<<1, SCAN_T, 0, stream>>>(cnt, rowptr, cursor, n);
    k_fill<<<(e + 255) / 256, 256, 0, stream>>>(erow, ecol, cursor, csr_src, e);

    dim3 aggGrid(((size_t)n * 64 + 255) / 256);
    dim3 mmGrid((n + MM_ROWS - 1) / MM_ROWS);

    // layer 1
    k_gcn_agg<<<aggGrid, 256, 0, stream>>>(x, csr_src, rowptr, dis, agg, n);
    k_mm_bias_relu<<<mmGrid, 256, 0, stream>>>(agg, W1, b1, bufA, n);
    // layer 2
    k_gcn_agg<<<aggGrid, 256, 0, stream>>>(bufA, csr_src, rowptr, dis, agg, n);
    k_mm_bias_relu<<<mmGrid, 256, 0, stream>>>(agg, W2, b2, bufB, n);
    // layer 3
    k_gcn_agg<<<aggGrid, 256, 0, stream>>>(bufB, csr_src, rowptr, dis, agg, n);
    k_mm_bias_relu<<<mmGrid, 256, 0, stream>>>(agg, W3, b3, bufA, n);

    // global mean pool (batch is sorted -> binary-searched ranges, no atomics)
    k_pool_graph<<<N_GRAPHS, 256, 0, stream>>>(bufA, batch, (float*)d_out, n);
}

// Round 4
// 589.368 us; speedup vs baseline: 8.4612x; 1.3710x over previous
//
#include <hip/hip_runtime.h>

#define DIM 128
#define N_GRAPHS 64
#define MM_ROWS 64

// ---------------- degree / CSR precompute ----------------

__global__ void k_count(const int* __restrict__ col, int* __restrict__ cnt, int e) {
    int i = blockIdx.x * blockDim.x + threadIdx.x;
    if (i < e) atomicAdd(&cnt[col[i]], 1);
}

// dis[i] = rsqrt(1 + in_degree)  (self loop included)
__global__ void k_make_dis(const int* __restrict__ cnt, float* __restrict__ dis, int n) {
    int i = blockIdx.x * blockDim.x + threadIdx.x;
    if (i < n) dis[i] = rsqrtf(1.0f + (float)cnt[i]);
}

// ---- parallel exclusive scan over cnt[n] -> rowptr[n+1], cursor[n] ----
// phase A: per-256-block sums
__global__ __launch_bounds__(256) void k_bsum(const int* __restrict__ cnt,
                                              int* __restrict__ bsum, int n) {
    __shared__ int s[256];
    int t = threadIdx.x;
    int i = blockIdx.x * 256 + t;
    s[t] = (i < n) ? cnt[i] : 0;
    __syncthreads();
    for (int o = 128; o > 0; o >>= 1) {
        if (t < o) s[t] += s[t + o];
        __syncthreads();
    }
    if (t == 0) bsum[blockIdx.x] = s[0];
}

// phase B: single-block exclusive scan of <=256 block sums
__global__ __launch_bounds__(256) void k_bscan(const int* __restrict__ bsum,
                                               int* __restrict__ bbase, int nb) {
    __shared__ int s[256];
    int t = threadIdx.x;
    int v = (t < nb) ? bsum[t] : 0;
    s[t] = v;
    __syncthreads();
    for (int o = 1; o < 256; o <<= 1) {
        int u = (t >= o) ? s[t - o] : 0;
        __syncthreads();
        s[t] += u;
        __syncthreads();
    }
    if (t < nb) bbase[t] = s[t] - v;  // exclusive
}

// phase C: per-block Hillis-Steele, one element per thread, + block base
__global__ __launch_bounds__(256) void k_bfinal(const int* __restrict__ cnt,
        const int* __restrict__ bbase, int* __restrict__ rowptr,
        int* __restrict__ cursor, int n, int e) {
    __shared__ int s[256];
    int t = threadIdx.x;
    int i = blockIdx.x * 256 + t;
    int v = (i < n) ? cnt[i] : 0;
    s[t] = v;
    __syncthreads();
    for (int o = 1; o < 256; o <<= 1) {
        int u = (t >= o) ? s[t - o] : 0;
        __syncthreads();
        s[t] += u;
        __syncthreads();
    }
    if (i < n) {
        int excl = s[t] - v + bbase[blockIdx.x];
        rowptr[i] = excl;
        cursor[i] = excl;
        if (i == n - 1) rowptr[n] = e;
    }
}

__global__ void k_fill(const int* __restrict__ row, const int* __restrict__ col,
                       int* __restrict__ cursor, int* __restrict__ csr_src, int e) {
    int i = blockIdx.x * blockDim.x + threadIdx.x;
    if (i >= e) return;
    int pos = atomicAdd(&cursor[col[i]], 1);
    csr_src[pos] = row[i];
}

// ---------------- aggregation: gather form, no atomics ----------------
// one wave per target node; lane l owns columns [2l, 2l+1]; edge loop unrolled x4
// so 4 independent 512B row-gathers are in flight per wave.

__global__ __launch_bounds__(256) void k_gcn_agg(const float* __restrict__ in,
        const int* __restrict__ csr_src, const int* __restrict__ rowptr,
        const float* __restrict__ dis, float* __restrict__ agg, int n) {
    int wid = (blockIdx.x * blockDim.x + threadIdx.x) >> 6;
    if (wid >= n) return;
    int lane = threadIdx.x & 63;
    const int coff = lane * 2;
    float d = dis[wid];
    float2 acc = *(const float2*)&in[(size_t)wid * DIM + coff];
    float dd = d * d;  // self-loop weight
    acc.x *= dd; acc.y *= dd;
    int p = rowptr[wid], p1 = rowptr[wid + 1];
    for (; p + 3 < p1; p += 4) {
        int s0 = csr_src[p], s1 = csr_src[p + 1], s2 = csr_src[p + 2], s3 = csr_src[p + 3];
        float w0 = d * dis[s0], w1 = d * dis[s1], w2 = d * dis[s2], w3 = d * dis[s3];
        float2 v0 = *(const float2*)&in[(size_t)s0 * DIM + coff];
        float2 v1 = *(const float2*)&in[(size_t)s1 * DIM + coff];
        float2 v2 = *(const float2*)&in[(size_t)s2 * DIM + coff];
        float2 v3 = *(const float2*)&in[(size_t)s3 * DIM + coff];
        acc.x += v0.x * w0; acc.y += v0.y * w0;
        acc.x += v1.x * w1; acc.y += v1.y * w1;
        acc.x += v2.x * w2; acc.y += v2.y * w2;
        acc.x += v3.x * w3; acc.y += v3.y * w3;
    }
    for (; p < p1; p++) {
        int s = csr_src[p];
        float w = d * dis[s];
        float2 v = *(const float2*)&in[(size_t)s * DIM + coff];
        acc.x += v.x * w;
        acc.y += v.y * w;
    }
    *(float2*)&agg[(size_t)wid * DIM + coff] = acc;
}

// ---------------- matmul + bias + relu ----------------
// 2 rows per wave (half-waves), lane owns 4 adjacent cols -> ds_read_b128 for W

__global__ __launch_bounds__(256) void k_mm_bias_relu(
        const float* __restrict__ A, const float* __restrict__ W,
        const float* __restrict__ bias, float* __restrict__ out, int n) {
    __shared__ float sW[DIM * DIM];  // 64 KB
    int tid = threadIdx.x;
    for (int i = tid * 4; i < DIM * DIM; i += 256 * 4) {
        *(float4*)&sW[i] = *(const float4*)&W[i];
    }
    __syncthreads();

    int wave = tid >> 6, lane = tid & 63;
    int half = lane >> 5;        // 0 or 1: which row of the pair
    int l32 = lane & 31;         // owns cols [4*l32, 4*l32+3]
    int hsel = lane & 32;        // shfl half-select
    float4 bv = *(const float4*)&bias[4 * l32];
    int base = blockIdx.x * MM_ROWS;

    for (int pr = wave; pr < MM_ROWS / 2; pr += 4) {
        int r = base + pr * 2 + half;
        bool valid = (r < n);
        const float* xr = &A[(size_t)(valid ? r : (n - 1)) * DIM];
        float x0 = xr[l32];
        float x1 = xr[l32 + 32];
        float x2 = xr[l32 + 64];
        float x3 = xr[l32 + 96];
        float4 acc = {0.f, 0.f, 0.f, 0.f};

#pragma unroll 8
        for (int k = 0; k < 32; k++) {
            float xk = __shfl(x0, k + hsel);
            float4 wv = *(const float4*)&sW[k * DIM + 4 * l32];
            acc.x += xk * wv.x; acc.y += xk * wv.y;
            acc.z += xk * wv.z; acc.w += xk * wv.w;
        }
#pragma unroll 8
        for (int k = 0; k < 32; k++) {
            float xk = __shfl(x1, k + hsel);
            float4 wv = *(const float4*)&sW[(k + 32) * DIM + 4 * l32];
            acc.x += xk * wv.x; acc.y += xk * wv.y;
            acc.z += xk * wv.z; acc.w += xk * wv.w;
        }
#pragma unroll 8
        for (int k = 0; k < 32; k++) {
            float xk = __shfl(x2, k + hsel);
            float4 wv = *(const float4*)&sW[(k + 64) * DIM + 4 * l32];
            acc.x += xk * wv.x; acc.y += xk * wv.y;
            acc.z += xk * wv.z; acc.w += xk * wv.w;
        }
#pragma unroll 8
        for (int k = 0; k < 32; k++) {
            float xk = __shfl(x3, k + hsel);
            float4 wv = *(const float4*)&sW[(k + 96) * DIM + 4 * l32];
            acc.x += xk * wv.x; acc.y += xk * wv.y;
            acc.z += xk * wv.z; acc.w += xk * wv.w;
        }

        if (valid) {
            float4 o;
            o.x = acc.x + bv.x; o.y = acc.y + bv.y;
            o.z = acc.z + bv.z; o.w = acc.w + bv.w;
            o.x = o.x > 0.f ? o.x : 0.f;
            o.y = o.y > 0.f ? o.y : 0.f;
            o.z = o.z > 0.f ? o.z : 0.f;
            o.w = o.w > 0.f ? o.w : 0.f;
            *(float4*)&out[(size_t)r * DIM + 4 * l32] = o;
        }
    }
}

// ---------------- global mean pool: one block per graph, no atomics ----------------

__global__ __launch_bounds__(256) void k_pool_graph(const float* __restrict__ h,
        const int* __restrict__ batch, float* __restrict__ out, int n) {
    int g = blockIdx.x;
    int lo = 0, hi = n;
    while (lo < hi) { int m = (lo + hi) >> 1; if (batch[m] < g) lo = m + 1; else hi = m; }
    int start = lo;
    int lo2 = start, hi2 = n;
    while (lo2 < hi2) { int m = (lo2 + hi2) >> 1; if (batch[m] < g + 1) lo2 = m + 1; else hi2 = m; }
    int end = lo2;

    int t = threadIdx.x;
    int wave = t >> 6, lane = t & 63;
    float2 acc = {0.f, 0.f};
    for (int r = start + wave; r < end; r += 4) {
        float2 v = *(const float2*)&h[(size_t)r * DIM + lane * 2];
        acc.x += v.x; acc.y += v.y;
    }
    __shared__ float2 part[4][64];
    part[wave][lane] = acc;
    __syncthreads();
    if (t < 64) {
        float2 s0 = part[0][t], s1 = part[1][t], s2 = part[2][t], s3 = part[3][t];
        float sx = s0.x + s1.x + s2.x + s3.x;
        float sy = s0.y + s1.y + s2.y + s3.y;
        float c = (float)(end - start);
        c = c > 1.f ? c : 1.f;
        out[g * DIM + t * 2] = sx / c;
        out[g * DIM + t * 2 + 1] = sy / c;
    }
}

// ---------------- launch ----------------

extern "C" void kernel_launch(void* const* d_in, const int* in_sizes, int n_in,
                              void* d_out, int out_size, void* d_ws, size_t ws_size,
                              hipStream_t stream) {
    const float* x  = (const float*)d_in[0];
    const int*   ei = (const int*)d_in[1];
    const int*   batch = (const int*)d_in[2];
    const float* W1 = (const float*)d_in[3];
    const float* b1 = (const float*)d_in[4];
    const float* W2 = (const float*)d_in[5];
    const float* b2 = (const float*)d_in[6];
    const float* W3 = (const float*)d_in[7];
    const float* b3 = (const float*)d_in[8];

    int n = in_sizes[0] / DIM;  // 50000
    int e = in_sizes[1] / 2;    // 800000
    const int* erow = ei;       // sources
    const int* ecol = ei + e;   // targets
    int nb = (n + 255) / 256;   // 196 scan blocks (<=256 required)

    char* ws = (char*)d_ws;
    size_t off = 0;
    auto alloc = [&](size_t bytes) -> void* {
        void* p = (void*)(ws + off);
        off += (bytes + 255) & ~(size_t)255;
        return p;
    };
    float* dis     = (float*)alloc((size_t)n * 4);
    int*   rowptr  = (int*)alloc((size_t)(n + 1) * 4);
    int*   csr_src = (int*)alloc((size_t)e * 4);
    float* agg     = (float*)alloc((size_t)n * DIM * 4);
    float* bufA    = (float*)alloc((size_t)n * DIM * 4);
    float* bufB    = (float*)alloc((size_t)n * DIM * 4);
    // transient CSR-build arrays overlap bufA (bufA first written in layer-1 mm)
    int* cnt    = (int*)bufA;
    int* cursor = ((int*)bufA) + n;
    int* bsum   = ((int*)bufA) + 2 * n;
    int* bbase  = ((int*)bufA) + 2 * n + 256;

    // ---- CSR build (once; edge_index is layer-invariant) ----
    hipMemsetAsync(cnt, 0, (size_t)n * 4, stream);
    k_count<<<(e + 255) / 256, 256, 0, stream>>>(ecol, cnt, e);
    k_make_dis<<<(n + 255) / 256, 256, 0, stream>>>(cnt, dis, n);
    k_bsum<<<nb, 256, 0, stream>>>(cnt, bsum, n);
    k_bscan<<<1, 256, 0, stream>>>(bsum, bbase, nb);
    k_bfinal<<<nb, 256, 0, stream>>>(cnt, bbase, rowptr, cursor, n, e);
    k_fill<<<(e + 255) / 256, 256, 0, stream>>>(erow, ecol, cursor, csr_src, e);

    dim3 aggGrid(((size_t)n * 64 + 255) / 256);
    dim3 mmGrid((n + MM_ROWS - 1) / MM_ROWS);

    // layer 1
    k_gcn_agg<<<aggGrid, 256, 0, stream>>>(x, csr_src, rowptr, dis, agg, n);
    k_mm_bias_relu<<<mmGrid, 256, 0, stream>>>(agg, W1, b1, bufA, n);
    // layer 2
    k_gcn_agg<<<aggGrid, 256, 0, stream>>>(bufA, csr_src, rowptr, dis, agg, n);
    k_mm_bias_relu<<<mmGrid, 256, 0, stream>>>(agg, W2, b2, bufB, n);
    // layer 3
    k_gcn_agg<<<aggGrid, 256, 0, stream>>>(bufB, csr_src, rowptr, dis, agg, n);
    k_mm_bias_relu<<<mmGrid, 256, 0, stream>>>(agg, W3, b3, bufA, n);

    // global mean pool (batch sorted -> binary-searched ranges, no atomics)
    k_pool_graph<<<N_GRAPHS, 256, 0, stream>>>(bufA, batch, (float*)d_out, n);
}

// Round 5
// 460.849 us; speedup vs baseline: 10.8209x; 1.2789x over previous
//
#include <hip/hip_runtime.h>

#define DIM 128
#define N_GRAPHS 64

typedef __attribute__((ext_vector_type(4))) float f32x4;
typedef __attribute__((ext_vector_type(8))) short s16x8;

// ---------------- degree / CSR precompute ----------------

__global__ void k_count(const int* __restrict__ col, int* __restrict__ cnt, int e) {
    int i = blockIdx.x * blockDim.x + threadIdx.x;
    if (i < e) atomicAdd(&cnt[col[i]], 1);
}

// dis[i] = rsqrt(1 + in_degree)  (self loop included)
__global__ void k_make_dis(const int* __restrict__ cnt, float* __restrict__ dis, int n) {
    int i = blockIdx.x * blockDim.x + threadIdx.x;
    if (i < n) dis[i] = rsqrtf(1.0f + (float)cnt[i]);
}

// ---- parallel exclusive scan over cnt[n] -> rowptr[n+1], cursor[n] ----
__global__ __launch_bounds__(256) void k_bsum(const int* __restrict__ cnt,
                                              int* __restrict__ bsum, int n) {
    __shared__ int s[256];
    int t = threadIdx.x;
    int i = blockIdx.x * 256 + t;
    s[t] = (i < n) ? cnt[i] : 0;
    __syncthreads();
    for (int o = 128; o > 0; o >>= 1) {
        if (t < o) s[t] += s[t + o];
        __syncthreads();
    }
    if (t == 0) bsum[blockIdx.x] = s[0];
}

__global__ __launch_bounds__(256) void k_bscan(const int* __restrict__ bsum,
                                               int* __restrict__ bbase, int nb) {
    __shared__ int s[256];
    int t = threadIdx.x;
    int v = (t < nb) ? bsum[t] : 0;
    s[t] = v;
    __syncthreads();
    for (int o = 1; o < 256; o <<= 1) {
        int u = (t >= o) ? s[t - o] : 0;
        __syncthreads();
        s[t] += u;
        __syncthreads();
    }
    if (t < nb) bbase[t] = s[t] - v;  // exclusive
}

__global__ __launch_bounds__(256) void k_bfinal(const int* __restrict__ cnt,
        const int* __restrict__ bbase, int* __restrict__ rowptr,
        int* __restrict__ cursor, int n, int e) {
    __shared__ int s[256];
    int t = threadIdx.x;
    int i = blockIdx.x * 256 + t;
    int v = (i < n) ? cnt[i] : 0;
    s[t] = v;
    __syncthreads();
    for (int o = 1; o < 256; o <<= 1) {
        int u = (t >= o) ? s[t - o] : 0;
        __syncthreads();
        s[t] += u;
        __syncthreads();
    }
    if (i < n) {
        int excl = s[t] - v + bbase[blockIdx.x];
        rowptr[i] = excl;
        cursor[i] = excl;
        if (i == n - 1) rowptr[n] = e;
    }
}

__global__ void k_fill(const int* __restrict__ row, const int* __restrict__ col,
                       int* __restrict__ cursor, int* __restrict__ csr_src, int e) {
    int i = blockIdx.x * blockDim.x + threadIdx.x;
    if (i >= e) return;
    int pos = atomicAdd(&cursor[col[i]], 1);
    csr_src[pos] = row[i];
}

// ---------------- aggregation: gather form, no atomics ----------------

__global__ __launch_bounds__(256) void k_gcn_agg(const float* __restrict__ in,
        const int* __restrict__ csr_src, const int* __restrict__ rowptr,
        const float* __restrict__ dis, float* __restrict__ agg, int n) {
    int wid = (blockIdx.x * blockDim.x + threadIdx.x) >> 6;
    if (wid >= n) return;
    int lane = threadIdx.x & 63;
    const int coff = lane * 2;
    float d = dis[wid];
    float2 acc = *(const float2*)&in[(size_t)wid * DIM + coff];
    float dd = d * d;  // self-loop weight
    acc.x *= dd; acc.y *= dd;
    int p = rowptr[wid], p1 = rowptr[wid + 1];
    for (; p + 3 < p1; p += 4) {
        int s0 = csr_src[p], s1 = csr_src[p + 1], s2 = csr_src[p + 2], s3 = csr_src[p + 3];
        float w0 = d * dis[s0], w1 = d * dis[s1], w2 = d * dis[s2], w3 = d * dis[s3];
        float2 v0 = *(const float2*)&in[(size_t)s0 * DIM + coff];
        float2 v1 = *(const float2*)&in[(size_t)s1 * DIM + coff];
        float2 v2 = *(const float2*)&in[(size_t)s2 * DIM + coff];
        float2 v3 = *(const float2*)&in[(size_t)s3 * DIM + coff];
        acc.x += v0.x * w0; acc.y += v0.y * w0;
        acc.x += v1.x * w1; acc.y += v1.y * w1;
        acc.x += v2.x * w2; acc.y += v2.y * w2;
        acc.x += v3.x * w3; acc.y += v3.y * w3;
    }
    for (; p < p1; p++) {
        int s = csr_src[p];
        float w = d * dis[s];
        float2 v = *(const float2*)&in[(size_t)s * DIM + coff];
        acc.x += v.x * w;
        acc.y += v.y * w;
    }
    *(float2*)&agg[(size_t)wid * DIM + coff] = acc;
}

// ---------------- bf16 helpers ----------------

__device__ __forceinline__ unsigned short bf16_rtne(float f) {
    unsigned u = __builtin_bit_cast(unsigned, f);
    unsigned r = u + 0x7FFFu + ((u >> 16) & 1u);
    return (unsigned short)(r >> 16);
}
__device__ __forceinline__ float bf16_to_f32(unsigned short h) {
    unsigned u = ((unsigned)h) << 16;
    return __builtin_bit_cast(float, u);
}

// W[k][c] (128x128 f32) -> Wt_hi[c][k], Wt_lo[c][k] (bf16 split)
__global__ __launch_bounds__(256) void k_wprep(const float* __restrict__ W,
        unsigned short* __restrict__ wt_hi, unsigned short* __restrict__ wt_lo) {
    int i = blockIdx.x * 256 + threadIdx.x;  // 16384 total
    int k = i >> 7, c = i & 127;
    float w = W[i];
    unsigned short h = bf16_rtne(w);
    unsigned short l = bf16_rtne(w - bf16_to_f32(h));
    wt_hi[c * DIM + k] = h;
    wt_lo[c * DIM + k] = l;
}

// ---------------- MFMA matmul + bias + relu ----------------
// out[r][:] = relu(A[r][:] @ W + b)
// 3-term bf16 split: A@W ~= Ah@Wh + Al@Wh + Ah@Wl
// 4 waves/block, 16 rows/wave, full 128 cols per wave.
// mfma_f32_16x16x32_bf16: A row=lane&15, k=(lane>>4)*8+j ; C col=lane&15, row=(lane>>4)*4+reg

__global__ __launch_bounds__(256) void k_mm_mfma(
        const float* __restrict__ A, const unsigned short* __restrict__ wt_hi,
        const unsigned short* __restrict__ wt_lo, const float* __restrict__ bias,
        float* __restrict__ out, int n) {
    int tid = threadIdx.x;
    int wave = tid >> 6, lane = tid & 63;
    int r0 = blockIdx.x * 64 + wave * 16;
    int lrow = lane & 15;          // A-frag / C col index
    int lk = lane >> 4;            // k-group 0..3
    int row = r0 + lrow;
    int rowc = row < n ? row : (n - 1);

    // load this lane's A slices and split to bf16 hi/lo
    const float* ar = A + (size_t)rowc * DIM;
    s16x8 ah[4], al[4];
#pragma unroll
    for (int ks = 0; ks < 4; ks++) {
        int kb = ks * 32 + lk * 8;
        float4 u0 = *(const float4*)&ar[kb];
        float4 u1 = *(const float4*)&ar[kb + 4];
        float v[8] = {u0.x, u0.y, u0.z, u0.w, u1.x, u1.y, u1.z, u1.w};
        s16x8 h, l;
#pragma unroll
        for (int j = 0; j < 8; j++) {
            unsigned short hb = bf16_rtne(v[j]);
            h[j] = (short)hb;
            l[j] = (short)bf16_rtne(v[j] - bf16_to_f32(hb));
        }
        ah[ks] = h; al[ks] = l;
    }

    f32x4 acc[8];
#pragma unroll
    for (int ct = 0; ct < 8; ct++) {
        const unsigned short* bh_base = wt_hi + (size_t)(ct * 16 + lrow) * DIM + lk * 8;
        const unsigned short* bl_base = wt_lo + (size_t)(ct * 16 + lrow) * DIM + lk * 8;
        s16x8 bh[4], bl[4];
#pragma unroll
        for (int ks = 0; ks < 4; ks++) {
            bh[ks] = *(const s16x8*)(bh_base + ks * 32);
            bl[ks] = *(const s16x8*)(bl_base + ks * 32);
        }
        f32x4 c = {0.f, 0.f, 0.f, 0.f};
#pragma unroll
        for (int ks = 0; ks < 4; ks++) {
            c = __builtin_amdgcn_mfma_f32_16x16x32_bf16(ah[ks], bh[ks], c, 0, 0, 0);
            c = __builtin_amdgcn_mfma_f32_16x16x32_bf16(al[ks], bh[ks], c, 0, 0, 0);
            c = __builtin_amdgcn_mfma_f32_16x16x32_bf16(ah[ks], bl[ks], c, 0, 0, 0);
        }
        acc[ct] = c;
    }

    // epilogue: bias + relu + store
#pragma unroll
    for (int ct = 0; ct < 8; ct++) {
        int col = ct * 16 + lrow;
        float bcol = bias[col];
#pragma unroll
        for (int reg = 0; reg < 4; reg++) {
            int orow = r0 + lk * 4 + reg;
            if (orow < n) {
                float v = acc[ct][reg] + bcol;
                out[(size_t)orow * DIM + col] = v > 0.f ? v : 0.f;
            }
        }
    }
}

// ---------------- global mean pool: one block per graph, no atomics ----------------

__global__ __launch_bounds__(256) void k_pool_graph(const float* __restrict__ h,
        const int* __restrict__ batch, float* __restrict__ out, int n) {
    int g = blockIdx.x;
    int lo = 0, hi = n;
    while (lo < hi) { int m = (lo + hi) >> 1; if (batch[m] < g) lo = m + 1; else hi = m; }
    int start = lo;
    int lo2 = start, hi2 = n;
    while (lo2 < hi2) { int m = (lo2 + hi2) >> 1; if (batch[m] < g + 1) lo2 = m + 1; else hi2 = m; }
    int end = lo2;

    int t = threadIdx.x;
    int wave = t >> 6, lane = t & 63;
    float2 acc = {0.f, 0.f};
    for (int r = start + wave; r < end; r += 4) {
        float2 v = *(const float2*)&h[(size_t)r * DIM + lane * 2];
        acc.x += v.x; acc.y += v.y;
    }
    __shared__ float2 part[4][64];
    part[wave][lane] = acc;
    __syncthreads();
    if (t < 64) {
        float2 s0 = part[0][t], s1 = part[1][t], s2 = part[2][t], s3 = part[3][t];
        float sx = s0.x + s1.x + s2.x + s3.x;
        float sy = s0.y + s1.y + s2.y + s3.y;
        float c = (float)(end - start);
        c = c > 1.f ? c : 1.f;
        out[g * DIM + t * 2] = sx / c;
        out[g * DIM + t * 2 + 1] = sy / c;
    }
}

// ---------------- launch ----------------

extern "C" void kernel_launch(void* const* d_in, const int* in_sizes, int n_in,
                              void* d_out, int out_size, void* d_ws, size_t ws_size,
                              hipStream_t stream) {
    const float* x  = (const float*)d_in[0];
    const int*   ei = (const int*)d_in[1];
    const int*   batch = (const int*)d_in[2];
    const float* W1 = (const float*)d_in[3];
    const float* b1 = (const float*)d_in[4];
    const float* W2 = (const float*)d_in[5];
    const float* b2 = (const float*)d_in[6];
    const float* W3 = (const float*)d_in[7];
    const float* b3 = (const float*)d_in[8];

    int n = in_sizes[0] / DIM;  // 50000
    int e = in_sizes[1] / 2;    // 800000
    const int* erow = ei;       // sources
    const int* ecol = ei + e;   // targets
    int nb = (n + 255) / 256;   // 196 scan blocks (<=256 required)

    char* ws = (char*)d_ws;
    size_t off = 0;
    auto alloc = [&](size_t bytes) -> void* {
        void* p = (void*)(ws + off);
        off += (bytes + 255) & ~(size_t)255;
        return p;
    };
    float* dis     = (float*)alloc((size_t)n * 4);
    int*   rowptr  = (int*)alloc((size_t)(n + 1) * 4);
    int*   csr_src = (int*)alloc((size_t)e * 4);
    float* agg     = (float*)alloc((size_t)n * DIM * 4);
    float* bufA    = (float*)alloc((size_t)n * DIM * 4);
    float* bufB    = (float*)alloc((size_t)n * DIM * 4);
    unsigned short* wt_hi1 = (unsigned short*)alloc(DIM * DIM * 2);
    unsigned short* wt_lo1 = (unsigned short*)alloc(DIM * DIM * 2);
    unsigned short* wt_hi2 = (unsigned short*)alloc(DIM * DIM * 2);
    unsigned short* wt_lo2 = (unsigned short*)alloc(DIM * DIM * 2);
    unsigned short* wt_hi3 = (unsigned short*)alloc(DIM * DIM * 2);
    unsigned short* wt_lo3 = (unsigned short*)alloc(DIM * DIM * 2);
    // transient CSR-build arrays overlap bufA (bufA first written in layer-1 mm)
    int* cnt    = (int*)bufA;
    int* cursor = ((int*)bufA) + n;
    int* bsum   = ((int*)bufA) + 2 * n;
    int* bbase  = ((int*)bufA) + 2 * n + 256;

    // ---- CSR build (once; edge_index is layer-invariant) ----
    hipMemsetAsync(cnt, 0, (size_t)n * 4, stream);
    k_count<<<(e + 255) / 256, 256, 0, stream>>>(ecol, cnt, e);
    k_make_dis<<<(n + 255) / 256, 256, 0, stream>>>(cnt, dis, n);
    k_bsum<<<nb, 256, 0, stream>>>(cnt, bsum, n);
    k_bscan<<<1, 256, 0, stream>>>(bsum, bbase, nb);
    k_bfinal<<<nb, 256, 0, stream>>>(cnt, bbase, rowptr, cursor, n, e);
    k_fill<<<(e + 255) / 256, 256, 0, stream>>>(erow, ecol, cursor, csr_src, e);

    // ---- weight prep (transposed bf16 hi/lo) ----
    k_wprep<<<64, 256, 0, stream>>>(W1, wt_hi1, wt_lo1);
    k_wprep<<<64, 256, 0, stream>>>(W2, wt_hi2, wt_lo2);
    k_wprep<<<64, 256, 0, stream>>>(W3, wt_hi3, wt_lo3);

    dim3 aggGrid(((size_t)n * 64 + 255) / 256);
    dim3 mmGrid((n + 63) / 64);

    // layer 1
    k_gcn_agg<<<aggGrid, 256, 0, stream>>>(x, csr_src, rowptr, dis, agg, n);
    k_mm_mfma<<<mmGrid, 256, 0, stream>>>(agg, wt_hi1, wt_lo1, b1, bufA, n);
    // layer 2
    k_gcn_agg<<<aggGrid, 256, 0, stream>>>(bufA, csr_src, rowptr, dis, agg, n);
    k_mm_mfma<<<mmGrid, 256, 0, stream>>>(agg, wt_hi2, wt_lo2, b2, bufB, n);
    // layer 3
    k_gcn_agg<<<aggGrid, 256, 0, stream>>>(bufB, csr_src, rowptr, dis, agg, n);
    k_mm_mfma<<<mmGrid, 256, 0, stream>>>(agg, wt_hi3, wt_lo3, b3, bufA, n);

    // global mean pool (batch sorted -> binary-searched ranges, no atomics)
    k_pool_graph<<<N_GRAPHS, 256, 0, stream>>>(bufA, batch, (float*)d_out, n);
}